// Round 1
// 160.792 us; speedup vs baseline: 1.1128x; 1.1128x over previous
//
#include <hip/hip_runtime.h>

// KeypointFlowLoss: mask is nonzero only at the B*K scattered keypoints
// (y0 = k*(H/K) distinct per k => no scatter collisions), so the full
// (L,B,2,H,W) reduction collapses to a gather over <=1088 pixels * L * 2ch
// = 8704 scattered floats.
//
// Previous version ran <<<1,1024>>> => all 8704 uncoalesced HBM-miss loads
// funneled through ONE CU (latency-bound, ~21 us). This version uses one
// thread per (keypoint, layer, channel): 34 blocks x 256 threads spread over
// 34 CUs / all 8 XCDs, overlapping the scattered miss latency. Two-kernel
// split (partials -> finalize) because denom needs the global masked count;
// per-block partial slots in d_ws are each written exactly once (no atomics,
// no zero-init of workspace required).

#define LL 4
#define BB 64
#define KK 17
#define HH 256
#define WW 256
#define GAMMA 0.8f

#define NKP (BB * KK)        // 1088 keypoints
#define NTH (NKP * LL * 2)   // 8704 = one thread per (kp, layer, channel)
#define BLK 256
#define NBLK (NTH / BLK)     // 34 (divides exactly: 34*256 == 8704)

__global__ __launch_bounds__(BLK) void kfl_gather(
    const float* __restrict__ pred,   // (L,B,2,H,W) fp32
    const int*   __restrict__ kps,    // (B,2,K,2)   int32
    float*       __restrict__ ws)     // [0:NBLK) wsse partials, [NBLK:2*NBLK) cnt partials
{
    const int t  = blockIdx.x * BLK + threadIdx.x;   // < NTH always
    const int kp = t >> 3;                           // keypoint index
    const int r  = t & 7;                            // r = i*2 + c

    const int b = kp / KK;
    const int k = kp - b * KK;
    const int* k0 = kps + ((b * 2 + 0) * KK + k) * 2;
    const int* k1 = kps + ((b * 2 + 1) * KK + k) * 2;
    const int x0 = k0[0], y0 = k0[1];
    const int dxi = k1[0] - x0, dyi = k1[1] - y0;

    float wsse = 0.0f, cnt = 0.0f;
    if (dxi | dyi) {                                 // mask = |(dx,dy)| > 0
        const int i = r >> 1, c = r & 1;
        const float wts[LL] = {GAMMA * GAMMA * GAMMA, GAMMA * GAMMA, GAMMA, 1.0f};
        const float d = c ? (float)dyi : (float)dxi;
        const size_t o = (size_t)i * (BB * 2 * HH * WW)
                       + (size_t)b * (2 * HH * WW)
                       + (size_t)c * (HH * WW)
                       + (size_t)y0 * WW + (size_t)x0;
        const float e = pred[o] - d;                 // the one scattered HBM load
        wsse = wts[i] * e * e;
        cnt  = (r == 0) ? 1.0f : 0.0f;               // count each masked kp once
    }

    // wave-64 shuffle reduction
#pragma unroll
    for (int off = 32; off > 0; off >>= 1) {
        wsse += __shfl_down(wsse, off, 64);
        cnt  += __shfl_down(cnt,  off, 64);
    }

    __shared__ float sw[4], sc[4];
    const int wave = threadIdx.x >> 6;
    const int lane = threadIdx.x & 63;
    if (lane == 0) { sw[wave] = wsse; sc[wave] = cnt; }
    __syncthreads();

    if (threadIdx.x == 0) {
        ws[blockIdx.x]        = sw[0] + sw[1] + sw[2] + sw[3];
        ws[NBLK + blockIdx.x] = sc[0] + sc[1] + sc[2] + sc[3];
    }
}

__global__ __launch_bounds__(64) void kfl_final(
    const float* __restrict__ ws,
    float*       __restrict__ out)
{
    const int lane = threadIdx.x;
    float v = (lane < NBLK) ? ws[lane]        : 0.0f;
    float c = (lane < NBLK) ? ws[NBLK + lane] : 0.0f;
#pragma unroll
    for (int off = 32; off > 0; off >>= 1) {
        v += __shfl_down(v, off, 64);
        c += __shfl_down(c, off, 64);
    }
    if (lane == 0) {
        out[0] = v / fmaxf(c * 2.0f, 1.0f);          // LOSS_WEIGHT = 1.0
    }
}

extern "C" void kernel_launch(void* const* d_in, const int* in_sizes, int n_in,
                              void* d_out, int out_size, void* d_ws, size_t ws_size,
                              hipStream_t stream) {
    const float* pred = (const float*)d_in[0];  // (4,64,2,256,256) fp32
    const int*   kps  = (const int*)d_in[1];    // (64,2,17,2) int32
    float*       out  = (float*)d_out;          // scalar fp32
    float*       ws   = (float*)d_ws;           // >= 2*NBLK floats
    (void)in_sizes; (void)n_in; (void)out_size; (void)ws_size;

    kfl_gather<<<NBLK, BLK, 0, stream>>>(pred, kps, ws);
    kfl_final<<<1, 64, 0, stream>>>(ws, out);
}